// Round 6
// baseline (8282.742 us; speedup 1.0000x reference)
//
#include <hip/hip_runtime.h>

#define DEVI __device__ __forceinline__

typedef __attribute__((ext_vector_type(8))) __bf16 bf16x8;
typedef __attribute__((ext_vector_type(4))) float f32x4;
typedef __attribute__((ext_vector_type(2))) float f32x2;

// ---------- scalar helpers ----------
DEVI unsigned short f2b(float f) {           // f32 -> bf16 (RNE)
  unsigned u = __float_as_uint(f);
  u = u + 0x7fffu + ((u >> 16) & 1u);
  return (unsigned short)(u >> 16);
}
DEVI float b2f(unsigned short h) { return __uint_as_float(((unsigned)h) << 16); }
DEVI float lo16(unsigned u) { return __uint_as_float(u << 16); }
DEVI float hi16(unsigned u) { return __uint_as_float(u & 0xffff0000u); }
DEVI float sigm(float x) { return 1.f / (1.f + __expf(-x)); }

// ---------- fp8 e4m3fn decode (pair); HI selector must be a literal ----------
#if __has_builtin(__builtin_amdgcn_cvt_pk_f32_fp8)
template <bool HI>
DEVI f32x2 fp8pair(unsigned u) { return __builtin_amdgcn_cvt_pk_f32_fp8(u, HI); }
#else
DEVI float fp8one(unsigned b) {
  unsigned s = (b & 0x80u) << 24;
  unsigned e = (b >> 3) & 0xF, m = b & 7;
  float v = (e == 0) ? (float)m * 0.001953125f
                     : __uint_as_float(((e + 120u) << 23) | (m << 20));
  return __uint_as_float(__float_as_uint(v) | s);
}
template <bool HI>
DEVI f32x2 fp8pair(unsigned u) {
  unsigned h = HI ? (u >> 16) : (u & 0xffffu);
  f32x2 r; r.x = fp8one(h & 0xff); r.y = fp8one(h >> 8); return r;
}
#endif
DEVI f32x2 fma2(f32x2 a, f32x2 b, f32x2 c) { return __builtin_elementwise_fma(a, b, c); }

// nearest-code encode by exhaustive scan (decode-consistent, one-time cost)
DEVI unsigned fp8enc(float v) {
  unsigned best = 0; float bd = 3.4e38f;
  for (unsigned c = 0; c < 256; ++c) {
    f32x2 d2 = fp8pair<false>(c);
    float d = fabsf(d2.x - v);
    if (d < bd) { bd = d; best = c; }   // NaN codes never win (d==NaN -> false)
  }
  return best;
}

// ---------- prep kernels ----------
__global__ void cvt_bf16(const float* __restrict__ in, unsigned short* __restrict__ out, int n) {
  for (int i = blockIdx.x * blockDim.x + threadIdx.x; i < n; i += gridDim.x * blockDim.x)
    out[i] = f2b(in[i]);
}

// Whh (2,1024,256) f32 -> fp8x4 uint out[d][q64][u256][g4]; uint = W[d][g*256+u][4q..4q+3]
__global__ void whh_pack(const float* __restrict__ W, unsigned* __restrict__ out) {
  int idx = blockIdx.x * blockDim.x + threadIdx.x;   // 131072 total
  if (idx >= 131072) return;
  int d = idx >> 16, rem = idx & 65535;
  int q = rem >> 10, rem2 = rem & 1023, u = rem2 >> 2, g = rem2 & 3;
  const float* w = W + (((size_t)d * 1024 + g * 256 + u) * 256 + 4 * q);
  unsigned o = 0;
  #pragma unroll
  for (int j = 0; j < 4; ++j) o |= fp8enc(w[j]) << (8 * j);
  out[idx] = o;
}

__global__ void bias_sum(const float* __restrict__ a, const float* __restrict__ b,
                         float* __restrict__ o, int n) {
  int i = blockIdx.x * blockDim.x + threadIdx.x;
  if (i < n) o[i] = a[i] + b[i];
}

__global__ void embed_gather(const int* __restrict__ ids, const float* __restrict__ tab,
                             unsigned short* __restrict__ out, int total) {
  for (int i = blockIdx.x * blockDim.x + threadIdx.x; i < total; i += gridDim.x * blockDim.x) {
    int bt = i >> 7, c = i & 127;
    out[i] = f2b(tab[(size_t)ids[bt] * 128 + c]);
  }
}

// ---------- GEMM: C[M,N] = act(A[M,K](lda) @ W[N,K]^T + bias[N]) -> bf16 ----------
// 64x256 tile, 4 waves; wave = 16 rows x 16 col-frags (A re-fetched only N/256 times).
template <int ACT, int AFP32, int PERM>
__global__ __launch_bounds__(256) void gemm_bt(const void* __restrict__ Av, int lda,
                                               const unsigned short* __restrict__ W,
                                               const float* __restrict__ bias,
                                               unsigned short* __restrict__ C,
                                               int M, int N, int K) {
  const int ntiles = N >> 8;
  const int mt = blockIdx.x / ntiles;
  const int nt = blockIdx.x - mt * ntiles;
  const int m0 = mt << 6, n0 = nt << 8;
  const int tid = threadIdx.x;
  const int w = tid >> 6, lane = tid & 63, r = lane & 15, q = lane >> 4;
  f32x4 acc[16];
  #pragma unroll
  for (int c = 0; c < 16; ++c) acc[c] = f32x4{0.f, 0.f, 0.f, 0.f};
  const int arow = m0 + w * 16 + r;
  const unsigned short* Ab = (const unsigned short*)Av;
  const float* Af = (const float*)Av;
  for (int k0 = 0; k0 < K; k0 += 32) {
    const int ka = k0 + q * 8;
    bf16x8 a;
    if constexpr (AFP32) {
      const float* ap = Af + (size_t)arow * lda + ka;
      float4 f0 = *(const float4*)ap;
      float4 f1 = *(const float4*)(ap + 4);
      union { unsigned short e[8]; bf16x8 v; } ua;
      ua.e[0] = f2b(f0.x); ua.e[1] = f2b(f0.y); ua.e[2] = f2b(f0.z); ua.e[3] = f2b(f0.w);
      ua.e[4] = f2b(f1.x); ua.e[5] = f2b(f1.y); ua.e[6] = f2b(f1.z); ua.e[7] = f2b(f1.w);
      a = ua.v;
    } else {
      a = *(const bf16x8*)(const void*)(Ab + (size_t)arow * lda + ka);
    }
    const unsigned short* wb = W + (size_t)(n0 + r) * K + ka;
    #pragma unroll
    for (int c = 0; c < 16; ++c) {
      bf16x8 b = *(const bf16x8*)(const void*)(wb + (size_t)c * 16 * K);
      acc[c] = __builtin_amdgcn_mfma_f32_16x16x32_bf16(a, b, acc[c], 0, 0, 0);
    }
  }
  // D layout (m89-verified): col = lane&15, row = (lane>>4)*4 + reg
  const int rbase = m0 + w * 16 + q * 4;
  #pragma unroll
  for (int c = 0; c < 16; ++c) {
    const int col = n0 + c * 16 + r;
    const float bv = bias[col];
    int oc = col;
    if constexpr (PERM) oc = (col & 1024) | ((col & 255) << 2) | ((col >> 8) & 3);
    #pragma unroll
    for (int i = 0; i < 4; ++i) {
      float v = acc[c][i] + bv;
      if constexpr (ACT) v = fmaxf(v, 0.f);
      C[(size_t)(rbase + i) * N + oc] = f2b(v);
    }
  }
}

// ---------- LSTM recurrence, 2 samples per block, fp8 weights ----------
// 512 threads: u = tid&255 owns unit u; kh = tid>>8 covers h-dims [kh*128, kh*128+128).
// Weights: uint[2][64][256][4] fp8 quads. xg: [B][T][2048] bf16 col = dir*1024+u*4+gate.
// Grid 128 fused (grp = blockIdx>>6) or 64 single-pathway.
__global__ __launch_bounds__(512) void lstm_rec(
    const unsigned* __restrict__ W0, const unsigned short* __restrict__ x0,
    unsigned short* __restrict__ o0, int os0, int oo0,
    const unsigned* __restrict__ W1, const unsigned short* __restrict__ x1,
    unsigned short* __restrict__ o1, int os1, int oo1, int T) {
  const int grp = blockIdx.x >> 6;
  const int rem = blockIdx.x & 63;
  const int dir = rem & 1, pr = rem >> 1;
  const int b0 = pr * 2;
  const int tid = threadIdx.x;
  const int u = tid & 255, kh = tid >> 8;
  const unsigned* __restrict__ W2 = grp ? W1 : W0;
  const unsigned short* __restrict__ xg = grp ? x1 : x0;
  unsigned short* __restrict__ out = grp ? o1 : o0;
  const int outStride = grp ? os1 : os0;
  const int outOff = grp ? oo1 : oo0;

  __shared__ float hs[2][256];
  __shared__ float4 part[2][256];
  if (tid < 256) { hs[0][tid] = 0.f; hs[1][tid] = 0.f; }
  float c0 = 0.f, c1 = 0.f;
  const uint4* __restrict__ W4 = (const uint4*)(W2 + (size_t)dir * 65536);
  const unsigned short* xb0 = xg + (size_t)b0 * T * 2048 + dir * 1024 + u * 4;
  const unsigned short* xb1 = xb0 + (size_t)T * 2048;
  unsigned short* ob0 = out + (size_t)b0 * T * outStride + outOff + dir * 256 + u;
  unsigned short* ob1 = ob0 + (size_t)T * outStride;
  const uint4* __restrict__ wbase = W4 + (size_t)(kh * 32) * 256 + u;
  const float4* __restrict__ h0q = (const float4*)&hs[0][kh * 128];
  const float4* __restrict__ h1q = (const float4*)&hs[1][kh * 128];
  __syncthreads();
  for (int ti = 0; ti < T; ++ti) {
    const int t = dir ? (T - 1 - ti) : ti;
    uint2 xv0, xv1;
    if (kh == 0) {
      xv0 = *(const uint2*)(xb0 + (size_t)t * 2048);
      xv1 = *(const uint2*)(xb1 + (size_t)t * 2048);
    }
    f32x2 ai0{0.f,0.f}, af0 = ai0, ag0 = ai0, ao0 = ai0;
    f32x2 ai1 = ai0, af1 = ai0, ag1 = ai0, ao1 = ai0;
    #pragma unroll 8
    for (int q = 0; q < 32; ++q) {
      const uint4 w4 = wbase[(size_t)q * 256];
      const float4 hA = h0q[q];   // broadcast, conflict-free
      const float4 hB = h1q[q];
      const f32x2 hA01{hA.x, hA.y}, hA23{hA.z, hA.w};
      const f32x2 hB01{hB.x, hB.y}, hB23{hB.z, hB.w};
      f32x2 wl, wh;
      wl = fp8pair<false>(w4.x); wh = fp8pair<true>(w4.x);
      ai0 = fma2(hA01, wl, ai0); ai0 = fma2(hA23, wh, ai0);
      ai1 = fma2(hB01, wl, ai1); ai1 = fma2(hB23, wh, ai1);
      wl = fp8pair<false>(w4.y); wh = fp8pair<true>(w4.y);
      af0 = fma2(hA01, wl, af0); af0 = fma2(hA23, wh, af0);
      af1 = fma2(hB01, wl, af1); af1 = fma2(hB23, wh, af1);
      wl = fp8pair<false>(w4.z); wh = fp8pair<true>(w4.z);
      ag0 = fma2(hA01, wl, ag0); ag0 = fma2(hA23, wh, ag0);
      ag1 = fma2(hB01, wl, ag1); ag1 = fma2(hB23, wh, ag1);
      wl = fp8pair<false>(w4.w); wh = fp8pair<true>(w4.w);
      ao0 = fma2(hA01, wl, ao0); ao0 = fma2(hA23, wh, ao0);
      ao1 = fma2(hB01, wl, ao1); ao1 = fma2(hB23, wh, ao1);
    }
    if (kh) {
      part[0][u] = make_float4(ai0.x + ai0.y, af0.x + af0.y, ag0.x + ag0.y, ao0.x + ao0.y);
      part[1][u] = make_float4(ai1.x + ai1.y, af1.x + af1.y, ag1.x + ag1.y, ao1.x + ao1.y);
    }
    __syncthreads();                 // partials published; all hs reads done
    if (kh == 0) {
      const float4 p0 = part[0][u];
      const float4 p1 = part[1][u];
      float gi0 = lo16(xv0.x) + ai0.x + ai0.y + p0.x;
      float gf0 = hi16(xv0.x) + af0.x + af0.y + p0.y;
      float gg0 = lo16(xv0.y) + ag0.x + ag0.y + p0.z;
      float go0 = hi16(xv0.y) + ao0.x + ao0.y + p0.w;
      float gi1 = lo16(xv1.x) + ai1.x + ai1.y + p1.x;
      float gf1 = hi16(xv1.x) + af1.x + af1.y + p1.y;
      float gg1 = lo16(xv1.y) + ag1.x + ag1.y + p1.z;
      float go1 = hi16(xv1.y) + ao1.x + ao1.y + p1.w;
      c0 = sigm(gf0) * c0 + sigm(gi0) * tanhf(gg0);
      c1 = sigm(gf1) * c1 + sigm(gi1) * tanhf(gg1);
      const float h0v = sigm(go0) * tanhf(c0);
      const float h1v = sigm(go1) * tanhf(c1);
      hs[0][u] = h0v;
      hs[1][u] = h1v;
      ob0[(size_t)t * outStride] = f2b(h0v);
      ob1[(size_t)t * outStride] = f2b(h1v);
    }
    __syncthreads();                 // new h visible to all
  }
}

// ---------- classifier layer 2 ----------
__global__ __launch_bounds__(256) void cls2_kernel(const unsigned short* __restrict__ h1,
                                                   const unsigned short* __restrict__ w2,
                                                   const float* __restrict__ b2,
                                                   float* __restrict__ logits, int M) {
  int idx = blockIdx.x * 256 + threadIdx.x;
  int row = idx >> 4, n = idx & 15;
  if (row >= M || n >= 15) return;
  const unsigned* hp = (const unsigned*)(h1 + (size_t)row * 512);
  const unsigned* wp = (const unsigned*)(w2 + (size_t)n * 512);
  float acc = 0.f;
  #pragma unroll 8
  for (int k = 0; k < 256; ++k) {
    unsigned uh = hp[k], uw = wp[k];
    acc = fmaf(lo16(uh), lo16(uw), acc);
    acc = fmaf(hi16(uh), hi16(uw), acc);
  }
  logits[(size_t)row * 16 + n] = acc + b2[n];
}

// ---------- CRF ----------
__global__ void crf_num(const float* __restrict__ logits, const int* __restrict__ tags,
                        const float* __restrict__ start, const float* __restrict__ end,
                        const float* __restrict__ trans, float* __restrict__ numout, int T) {
  int b = threadIdx.x;   // 64 threads
  const int* tg = tags + (size_t)b * T;
  int prev = tg[0];
  float num = start[prev] + logits[((size_t)b * T) * 16 + prev];
  for (int t = 1; t < T; ++t) {
    int cur = tg[t];
    num += trans[prev * 15 + cur] + logits[((size_t)b * T + t) * 16 + cur];
    prev = cur;
  }
  num += end[prev];
  numout[b] = num;
}

__global__ void crf_denom(const float* __restrict__ logits, const float* __restrict__ start,
                          const float* __restrict__ end, const float* __restrict__ trans,
                          float* __restrict__ denout, int T) {
  int b = blockIdx.x;
  int lane = threadIdx.x;
  int kp = lane < 15 ? lane : 0;
  float tcol[15];
  #pragma unroll
  for (int k = 0; k < 15; ++k) tcol[k] = trans[k * 15 + kp];
  float score = start[kp] + logits[((size_t)b * T) * 16 + kp];
  for (int t = 1; t < T; ++t) {
    float e = logits[((size_t)b * T + t) * 16 + kp];
    float s[15], m = -3.4e38f;
    #pragma unroll
    for (int k = 0; k < 15; ++k) {
      s[k] = __shfl(score, k, 64) + tcol[k];
      m = fmaxf(m, s[k]);
    }
    float sum = 0.f;
    #pragma unroll
    for (int k = 0; k < 15; ++k) sum += __expf(s[k] - m);
    score = e + m + __logf(sum);
  }
  float x = score + end[kp];
  float m = -3.4e38f;
  #pragma unroll
  for (int k = 0; k < 15; ++k) m = fmaxf(m, __shfl(x, k, 64));
  float sum = 0.f;
  #pragma unroll
  for (int k = 0; k < 15; ++k) sum += __expf(__shfl(x, k, 64) - m);
  if (lane == 0) denout[b] = m + __logf(sum);
}

__global__ void crf_final(const float* __restrict__ num, const float* __restrict__ den,
                          float* __restrict__ out) {
  int l = threadIdx.x;
  float v = den[l] - num[l];
  #pragma unroll
  for (int off = 32; off > 0; off >>= 1) v += __shfl_xor(v, off, 64);
  if (l == 0) out[0] = v * (1.f / 64.f);
}

// ---------- host ----------
extern "C" void kernel_launch(void* const* d_in, const int* in_sizes, int n_in,
                              void* d_out, int out_size, void* d_ws, size_t ws_size,
                              hipStream_t stream) {
  const int B = 64, T = 512, M = B * T;   // 32768
  const float* we   = (const float*)d_in[1];
  const int*   cid  = (const int*)d_in[0];
  const int*   tags = (const int*)d_in[2];
  const float* etab = (const float*)d_in[3];

  char* ws = (char*)d_ws;
  size_t off = 0;
  auto alloc = [&](size_t bytes) -> char* {
    char* p = ws + off;
    off += (bytes + 255) & ~(size_t)255;
    return p;
  };
  // small, permanent
  unsigned short* wih_c0 = (unsigned short*)alloc((size_t)2048 * 128 * 2);
  unsigned short* wih_c1 = (unsigned short*)alloc((size_t)2048 * 512 * 2);
  unsigned short* wih_w0 = (unsigned short*)alloc((size_t)2048 * 768 * 2);
  unsigned short* wih_w1 = (unsigned short*)alloc((size_t)2048 * 512 * 2);
  unsigned short* cls1b  = (unsigned short*)alloc((size_t)512 * 1024 * 2);
  unsigned short* cls2b  = (unsigned short*)alloc((size_t)15 * 512 * 2);
  unsigned* whh_c0 = (unsigned*)alloc((size_t)131072 * 4);
  unsigned* whh_c1 = (unsigned*)alloc((size_t)131072 * 4);
  unsigned* whh_w0 = (unsigned*)alloc((size_t)131072 * 4);
  unsigned* whh_w1 = (unsigned*)alloc((size_t)131072 * 4);
  float* bs_c0 = (float*)alloc(2048 * 4);
  float* bs_c1 = (float*)alloc(2048 * 4);
  float* bs_w0 = (float*)alloc(2048 * 4);
  float* bs_w1 = (float*)alloc(2048 * 4);
  float* numb = (float*)alloc(64 * 4);
  float* denb = (float*)alloc(64 * 4);
  // big
  unsigned short* comb = (unsigned short*)alloc((size_t)M * 1024 * 2);   // 64 MB
  unsigned short* xg_c = (unsigned short*)alloc((size_t)M * 2048 * 2);   // 128 MB
  const size_t xgw_bytes = (size_t)M * 2048 * 2;
  const bool fused = (off + xgw_bytes) <= ws_size;
  unsigned short* xg_w;
  unsigned short* ce_b;
  if (fused) {
    xg_w = (unsigned short*)alloc(xgw_bytes);
    ce_b = xg_w;                                   // gemm c0 consumes before gemm w0 writes
  } else {
    xg_w = xg_c;
    ce_b = (unsigned short*)alloc((size_t)M * 128 * 2);
  }
  unsigned short* h1 = xg_c;                        // free after level-1 lstm
  float* logits = (float*)(xg_c + (size_t)24 * 1024 * 1024);   // +48MB into xg_c

  // ---- prep ----
  cvt_bf16<<<1024, 256, 0, stream>>>((const float*)d_in[4],  wih_c0, 2048 * 128);
  cvt_bf16<<<1024, 256, 0, stream>>>((const float*)d_in[8],  wih_c1, 2048 * 512);
  cvt_bf16<<<1024, 256, 0, stream>>>((const float*)d_in[12], wih_w0, 2048 * 768);
  cvt_bf16<<<1024, 256, 0, stream>>>((const float*)d_in[16], wih_w1, 2048 * 512);
  cvt_bf16<<<1024, 256, 0, stream>>>((const float*)d_in[20], cls1b, 512 * 1024);
  cvt_bf16<<<64, 256, 0, stream>>>((const float*)d_in[22], cls2b, 15 * 512);
  whh_pack<<<512, 256, 0, stream>>>((const float*)d_in[5],  whh_c0);
  whh_pack<<<512, 256, 0, stream>>>((const float*)d_in[9],  whh_c1);
  whh_pack<<<512, 256, 0, stream>>>((const float*)d_in[13], whh_w0);
  whh_pack<<<512, 256, 0, stream>>>((const float*)d_in[17], whh_w1);
  bias_sum<<<8, 256, 0, stream>>>((const float*)d_in[6],  (const float*)d_in[7],  bs_c0, 2048);
  bias_sum<<<8, 256, 0, stream>>>((const float*)d_in[10], (const float*)d_in[11], bs_c1, 2048);
  bias_sum<<<8, 256, 0, stream>>>((const float*)d_in[14], (const float*)d_in[15], bs_w0, 2048);
  bias_sum<<<8, 256, 0, stream>>>((const float*)d_in[18], (const float*)d_in[19], bs_w1, 2048);
  embed_gather<<<8192, 256, 0, stream>>>(cid, etab, ce_b, M * 128);

  if (fused) {
    gemm_bt<0, 0, 1><<<512 * 8, 256, 0, stream>>>(ce_b, 128, wih_c0, bs_c0, xg_c, M, 2048, 128);
    gemm_bt<0, 1, 1><<<512 * 8, 256, 0, stream>>>(we, 768, wih_w0, bs_w0, xg_w, M, 2048, 768);
    lstm_rec<<<128, 512, 0, stream>>>(whh_c0, xg_c, comb, 1024, 0,
                                      whh_w0, xg_w, comb, 1024, 512, T);
    gemm_bt<0, 0, 1><<<512 * 8, 256, 0, stream>>>(comb, 1024, wih_c1, bs_c1, xg_c, M, 2048, 512);
    gemm_bt<0, 0, 1><<<512 * 8, 256, 0, stream>>>(comb + 512, 1024, wih_w1, bs_w1, xg_w, M, 2048, 512);
    lstm_rec<<<128, 512, 0, stream>>>(whh_c1, xg_c, comb, 1024, 0,
                                      whh_w1, xg_w, comb, 1024, 512, T);
  } else {
    gemm_bt<0, 0, 1><<<512 * 8, 256, 0, stream>>>(ce_b, 128, wih_c0, bs_c0, xg_c, M, 2048, 128);
    lstm_rec<<<64, 512, 0, stream>>>(whh_c0, xg_c, comb, 1024, 0,
                                     whh_c0, xg_c, comb, 1024, 0, T);
    gemm_bt<0, 0, 1><<<512 * 8, 256, 0, stream>>>(comb, 1024, wih_c1, bs_c1, xg_c, M, 2048, 512);
    lstm_rec<<<64, 512, 0, stream>>>(whh_c1, xg_c, comb, 1024, 0,
                                     whh_c1, xg_c, comb, 1024, 0, T);
    gemm_bt<0, 1, 1><<<512 * 8, 256, 0, stream>>>(we, 768, wih_w0, bs_w0, xg_c, M, 2048, 768);
    lstm_rec<<<64, 512, 0, stream>>>(whh_w0, xg_c, comb, 1024, 512,
                                     whh_w0, xg_c, comb, 1024, 512, T);
    gemm_bt<0, 0, 1><<<512 * 8, 256, 0, stream>>>(comb + 512, 1024, wih_w1, bs_w1, xg_c, M, 2048, 512);
    lstm_rec<<<64, 512, 0, stream>>>(whh_w1, xg_c, comb, 1024, 512,
                                     whh_w1, xg_c, comb, 1024, 512, T);
  }
  // ---- classifier ----
  gemm_bt<1, 0, 0><<<512 * 2, 256, 0, stream>>>(comb, 1024, cls1b, (const float*)d_in[21], h1, M, 512, 1024);
  cls2_kernel<<<2048, 256, 0, stream>>>(h1, cls2b, (const float*)d_in[23], logits, M);
  // ---- CRF ----
  crf_num<<<1, 64, 0, stream>>>(logits, tags, (const float*)d_in[24], (const float*)d_in[25],
                                (const float*)d_in[26], numb, T);
  crf_denom<<<64, 64, 0, stream>>>(logits, (const float*)d_in[24], (const float*)d_in[25],
                                   (const float*)d_in[26], denb, T);
  crf_final<<<1, 64, 0, stream>>>(numb, denb, (float*)d_out);
}

// Round 7
// 7369.958 us; speedup vs baseline: 1.1239x; 1.1239x over previous
//
#include <hip/hip_runtime.h>

#define DEVI __device__ __forceinline__

typedef __attribute__((ext_vector_type(8))) __bf16 bf16x8;
typedef __attribute__((ext_vector_type(4))) float f32x4;
typedef __attribute__((ext_vector_type(2))) float f32x2;

// ---------- scalar helpers ----------
DEVI unsigned short f2b(float f) {           // f32 -> bf16 (RNE)
  unsigned u = __float_as_uint(f);
  u = u + 0x7fffu + ((u >> 16) & 1u);
  return (unsigned short)(u >> 16);
}
DEVI float lo16(unsigned u) { return __uint_as_float(u << 16); }
DEVI float hi16(unsigned u) { return __uint_as_float(u & 0xffff0000u); }
#if __has_builtin(__builtin_amdgcn_rcpf)
DEVI float rcpf(float x) { return __builtin_amdgcn_rcpf(x); }
#else
DEVI float rcpf(float x) { return 1.f / x; }
#endif
DEVI float sigm(float x) { return rcpf(1.f + __expf(-x)); }
DEVI float tanh_f(float x) { return fmaf(2.f, rcpf(1.f + __expf(-2.f * x)), -1.f); }

// ---------- fp8 e4m3fn encode/decode ----------
#if __has_builtin(__builtin_amdgcn_cvt_pk_fp8_f32)
DEVI unsigned char f2e4m3(float f) {
  return (unsigned char)(__builtin_amdgcn_cvt_pk_fp8_f32(f, f, 0, false) & 0xff);
}
#else
DEVI unsigned char f2e4m3(float f) {   // software RNE e4m3fn
  unsigned u = __float_as_uint(f);
  unsigned s = (u >> 31) << 7;
  float a = fabsf(f);
  if (a >= 448.f) return (unsigned char)(s | 0x7e);
  if (a < 0.015625f) {                 // denorm, unit 2^-9
    int m = (int)rintf(a * 512.f);
    if (m >= 8) return (unsigned char)(s | 0x08);
    return (unsigned char)(s | m);
  }
  unsigned ur = u + 0x7FFFF + ((u >> 20) & 1);   // RNE at mantissa bit 20
  int e8 = (int)((ur >> 23) & 255) - 127 + 7;
  unsigned m3 = (ur >> 20) & 7;
  if (e8 > 15 || (e8 == 15 && m3 > 6)) return (unsigned char)(s | 0x7e);
  if (e8 <= 0) return (unsigned char)s;
  return (unsigned char)(s | (e8 << 3) | m3);
}
#endif

// ---------- prep kernels ----------
__global__ void cvt_bf16(const float* __restrict__ in, unsigned short* __restrict__ out, int n) {
  for (int i = blockIdx.x * blockDim.x + threadIdx.x; i < n; i += gridDim.x * blockDim.x)
    out[i] = f2b(in[i]);
}

// Whh (2,1024,256) f32 -> fp8 MFMA-A-fragment order:
// uint2 index = ((d*64 + mt)*8 + kf)*64 + lane; bytes j=0..7:
//   row = mt*16 + (lane&15); unit = row>>2; gate = row&3;
//   k = kf*32 + (lane>>4)*8 + j;  src = W[d][gate*256 + unit][k]
__global__ void whh_pack(const float* __restrict__ W, uint2* __restrict__ out) {
  int idx = blockIdx.x * blockDim.x + threadIdx.x;   // 65536 total
  if (idx >= 65536) return;
  int d = idx >> 15, rem = idx & 32767;
  int mt = rem >> 9, kf = (rem >> 6) & 7, lane = rem & 63;
  int row = mt * 16 + (lane & 15);
  int unit = row >> 2, gate = row & 3;
  int kb = kf * 32 + (lane >> 4) * 8;
  const float* w = W + (((size_t)d * 1024 + gate * 256 + unit) * 256 + kb);
  unsigned lo = 0, hi = 0;
  #pragma unroll
  for (int j = 0; j < 4; ++j) lo |= (unsigned)f2e4m3(w[j]) << (8 * j);
  #pragma unroll
  for (int j = 0; j < 4; ++j) hi |= (unsigned)f2e4m3(w[4 + j]) << (8 * j);
  out[idx] = make_uint2(lo, hi);
}

__global__ void bias_sum(const float* __restrict__ a, const float* __restrict__ b,
                         float* __restrict__ o, int n) {
  int i = blockIdx.x * blockDim.x + threadIdx.x;
  if (i < n) o[i] = a[i] + b[i];
}

__global__ void embed_gather(const int* __restrict__ ids, const float* __restrict__ tab,
                             unsigned short* __restrict__ out, int total) {
  for (int i = blockIdx.x * blockDim.x + threadIdx.x; i < total; i += gridDim.x * blockDim.x) {
    int bt = i >> 7, c = i & 127;
    out[i] = f2b(tab[(size_t)ids[bt] * 128 + c]);
  }
}

// ---------- GEMM: C[M,N] = act(A[M,K](lda) @ W[N,K]^T + bias[N]) -> bf16 ----------
// 64x256 tile, 4 waves; wave = 16 rows x 16 col-frags.
template <int ACT, int AFP32, int PERM>
__global__ __launch_bounds__(256) void gemm_bt(const void* __restrict__ Av, int lda,
                                               const unsigned short* __restrict__ W,
                                               const float* __restrict__ bias,
                                               unsigned short* __restrict__ C,
                                               int M, int N, int K) {
  const int ntiles = N >> 8;
  const int mt = blockIdx.x / ntiles;
  const int nt = blockIdx.x - mt * ntiles;
  const int m0 = mt << 6, n0 = nt << 8;
  const int tid = threadIdx.x;
  const int w = tid >> 6, lane = tid & 63, r = lane & 15, q = lane >> 4;
  f32x4 acc[16];
  #pragma unroll
  for (int c = 0; c < 16; ++c) acc[c] = f32x4{0.f, 0.f, 0.f, 0.f};
  const int arow = m0 + w * 16 + r;
  const unsigned short* Ab = (const unsigned short*)Av;
  const float* Af = (const float*)Av;
  for (int k0 = 0; k0 < K; k0 += 32) {
    const int ka = k0 + q * 8;
    bf16x8 a;
    if constexpr (AFP32) {
      const float* ap = Af + (size_t)arow * lda + ka;
      float4 f0 = *(const float4*)ap;
      float4 f1 = *(const float4*)(ap + 4);
      union { unsigned short e[8]; bf16x8 v; } ua;
      ua.e[0] = f2b(f0.x); ua.e[1] = f2b(f0.y); ua.e[2] = f2b(f0.z); ua.e[3] = f2b(f0.w);
      ua.e[4] = f2b(f1.x); ua.e[5] = f2b(f1.y); ua.e[6] = f2b(f1.z); ua.e[7] = f2b(f1.w);
      a = ua.v;
    } else {
      a = *(const bf16x8*)(const void*)(Ab + (size_t)arow * lda + ka);
    }
    const unsigned short* wb = W + (size_t)(n0 + r) * K + ka;
    #pragma unroll
    for (int c = 0; c < 16; ++c) {
      bf16x8 b = *(const bf16x8*)(const void*)(wb + (size_t)c * 16 * K);
      acc[c] = __builtin_amdgcn_mfma_f32_16x16x32_bf16(a, b, acc[c], 0, 0, 0);
    }
  }
  // D layout (m89-verified): col = lane&15, row = (lane>>4)*4 + reg
  const int rbase = m0 + w * 16 + q * 4;
  #pragma unroll
  for (int c = 0; c < 16; ++c) {
    const int col = n0 + c * 16 + r;
    const float bv = bias[col];
    int oc = col;
    if constexpr (PERM) oc = (col & 1024) | ((col & 255) << 2) | ((col >> 8) & 3);
    #pragma unroll
    for (int i = 0; i < 4; ++i) {
      float v = acc[c][i] + bv;
      if constexpr (ACT) v = fmaxf(v, 0.f);
      C[(size_t)(rbase + i) * N + oc] = f2b(v);
    }
  }
}

// ---------- LSTM recurrence via MFMA fp8, 16 samples per block ----------
// Block = (pathway, dir, sample-group of 16). 1024 threads = 16 waves.
// Gate-rows ordered unit*4+gate so C-frag lane (q=lane>>4,n=lane&15) holds all 4 gates
// of unit (mt*4+q), sample n  [C/D: col=lane&15, row=(lane>>4)*4+reg, m89-verified].
// Wave w owns M-tiles mt = w*4+j (j=0..3) => units w*16 + j*4 + q. c-state in registers.
// h lives in LDS as fp8 B-fragments, ping-pong buffers; ONE barrier per step.
// xg: [B][T][2048] bf16, col = dir*1024 + u*4 + gate (bias included).
__global__ __launch_bounds__(1024) void lstm_mfma(
    const uint2* __restrict__ W0, const unsigned short* __restrict__ x0,
    unsigned short* __restrict__ o0, int oo0,
    const uint2* __restrict__ W1, const unsigned short* __restrict__ x1,
    unsigned short* __restrict__ o1, int oo1, int T) {
  const int bid = blockIdx.x;
  const int sg = bid & 3, dir = (bid >> 2) & 1, grp = bid >> 3;
  const uint2* __restrict__ Wp = (grp ? W1 : W0) + (size_t)dir * 32768;
  const unsigned short* __restrict__ xg = grp ? x1 : x0;
  unsigned short* __restrict__ out = grp ? o1 : o0;
  const int outOff = grp ? oo1 : oo0;

  const int tid = threadIdx.x;
  const int w = tid >> 6, lane = tid & 63, q = lane >> 4, n = lane & 15;
  const int b = sg * 16 + n;

  __shared__ long hb[2][512];          // [buf][kgroup32*16 + q*... ] fp8 h, 4KB each
  hb[0][tid % 512] = 0;                // 1024 threads -> each long written twice, fine
  hb[1][tid % 512] = 0;

  f32x4 acc[4];
  float c[4] = {0.f, 0.f, 0.f, 0.f};
  const unsigned short* xb = xg + ((size_t)b * T) * 2048 + dir * 1024;
  unsigned short* ob = out + ((size_t)b * T) * 1024 + outOff + dir * 256;
  int u_[4];
  #pragma unroll
  for (int j = 0; j < 4; ++j) u_[j] = w * 16 + j * 4 + q;
  __syncthreads();

  int cur = 0;
  for (int ti = 0; ti < T; ++ti) {
    const int t = dir ? (T - 1 - ti) : ti;
    // B-fragments (shared across this wave's M-tiles): byte kf*512 + q*128 + n*8
    long bf[8];
    #pragma unroll
    for (int kf = 0; kf < 8; ++kf) bf[kf] = hb[cur][kf * 64 + q * 16 + n];
    // xg gate biases for this lane's 4 units (consumed late -> latency hidden)
    uint2 xv[4];
    #pragma unroll
    for (int j = 0; j < 4; ++j)
      xv[j] = *(const uint2*)(xb + (size_t)t * 2048 + u_[j] * 4);
    // MFMA: acc[j] = Whh-tile(mt=w*4+j) x h
    #pragma unroll
    for (int j = 0; j < 4; ++j) {
      acc[j] = f32x4{0.f, 0.f, 0.f, 0.f};
      const uint2* ap = Wp + (size_t)((w * 4 + j) * 8) * 64 + lane;
      #pragma unroll
      for (int kf = 0; kf < 8; ++kf) {
        long a = __builtin_bit_cast(long, ap[(size_t)kf * 64]);
        acc[j] = __builtin_amdgcn_mfma_f32_16x16x32_fp8_fp8(a, bf[kf], acc[j], 0, 0, 0);
      }
    }
    // cell update: lane owns (unit u_[j], sample n) fully
    unsigned char* hw = (unsigned char*)&hb[cur ^ 1][0];
    #pragma unroll
    for (int j = 0; j < 4; ++j) {
      const float gi = acc[j][0] + lo16(xv[j].x);
      const float gf = acc[j][1] + hi16(xv[j].x);
      const float gg = acc[j][2] + lo16(xv[j].y);
      const float go = acc[j][3] + hi16(xv[j].y);
      c[j] = sigm(gf) * c[j] + sigm(gi) * tanh_f(gg);
      const float h = sigm(go) * tanh_f(c[j]);
      ob[(size_t)t * 1024 + u_[j]] = f2b(h);
      hw[(u_[j] >> 3) * 128 + n * 8 + (u_[j] & 7)] = f2e4m3(h);
    }
    __syncthreads();                   // new h visible; old buffer free
    cur ^= 1;
  }
}

// ---------- classifier layer 2 ----------
__global__ __launch_bounds__(256) void cls2_kernel(const unsigned short* __restrict__ h1,
                                                   const unsigned short* __restrict__ w2,
                                                   const float* __restrict__ b2,
                                                   float* __restrict__ logits, int M) {
  int idx = blockIdx.x * 256 + threadIdx.x;
  int row = idx >> 4, n = idx & 15;
  if (row >= M || n >= 15) return;
  const unsigned* hp = (const unsigned*)(h1 + (size_t)row * 512);
  const unsigned* wp = (const unsigned*)(w2 + (size_t)n * 512);
  float acc = 0.f;
  #pragma unroll 8
  for (int k = 0; k < 256; ++k) {
    unsigned uh = hp[k], uw = wp[k];
    acc = fmaf(lo16(uh), lo16(uw), acc);
    acc = fmaf(hi16(uh), hi16(uw), acc);
  }
  logits[(size_t)row * 16 + n] = acc + b2[n];
}

// ---------- CRF ----------
// numerator: parallel over t (associative sum), one block per sample
__global__ __launch_bounds__(256) void crf_num(const float* __restrict__ logits,
                                               const int* __restrict__ tags,
                                               const float* __restrict__ start,
                                               const float* __restrict__ end,
                                               const float* __restrict__ trans,
                                               float* __restrict__ numout, int T) {
  int b = blockIdx.x, tid = threadIdx.x;
  const int* tg = tags + (size_t)b * T;
  float s = 0.f;
  for (int t = tid; t < T; t += 256) {
    int cur = tg[t];
    s += logits[((size_t)b * T + t) * 16 + cur];
    if (t > 0) s += trans[tg[t - 1] * 15 + cur];
  }
  #pragma unroll
  for (int off = 32; off > 0; off >>= 1) s += __shfl_down(s, off, 64);
  __shared__ float red[4];
  if ((tid & 63) == 0) red[tid >> 6] = s;
  __syncthreads();
  if (tid == 0)
    numout[b] = red[0] + red[1] + red[2] + red[3] + start[tg[0]] + end[tg[T - 1]];
}

__global__ void crf_denom(const float* __restrict__ logits, const float* __restrict__ start,
                          const float* __restrict__ end, const float* __restrict__ trans,
                          float* __restrict__ denout, int T) {
  int b = blockIdx.x;
  int lane = threadIdx.x;
  int kp = lane < 15 ? lane : 0;
  float tcol[15];
  #pragma unroll
  for (int k = 0; k < 15; ++k) tcol[k] = trans[k * 15 + kp];
  float score = start[kp] + logits[((size_t)b * T) * 16 + kp];
  for (int t = 1; t < T; ++t) {
    float e = logits[((size_t)b * T + t) * 16 + kp];
    float s[15], m = -3.4e38f;
    #pragma unroll
    for (int k = 0; k < 15; ++k) {
      s[k] = __shfl(score, k, 64) + tcol[k];
      m = fmaxf(m, s[k]);
    }
    float sum = 0.f;
    #pragma unroll
    for (int k = 0; k < 15; ++k) sum += __expf(s[k] - m);
    score = e + m + __logf(sum);
  }
  float x = score + end[kp];
  float m = -3.4e38f;
  #pragma unroll
  for (int k = 0; k < 15; ++k) m = fmaxf(m, __shfl(x, k, 64));
  float sum = 0.f;
  #pragma unroll
  for (int k = 0; k < 15; ++k) sum += __expf(__shfl(x, k, 64) - m);
  if (lane == 0) denout[b] = m + __logf(sum);
}

__global__ void crf_final(const float* __restrict__ num, const float* __restrict__ den,
                          float* __restrict__ out) {
  int l = threadIdx.x;
  float v = den[l] - num[l];
  #pragma unroll
  for (int off = 32; off > 0; off >>= 1) v += __shfl_xor(v, off, 64);
  if (l == 0) out[0] = v * (1.f / 64.f);
}

// ---------- host ----------
extern "C" void kernel_launch(void* const* d_in, const int* in_sizes, int n_in,
                              void* d_out, int out_size, void* d_ws, size_t ws_size,
                              hipStream_t stream) {
  const int B = 64, T = 512, M = B * T;   // 32768
  const float* we   = (const float*)d_in[1];
  const int*   cid  = (const int*)d_in[0];
  const int*   tags = (const int*)d_in[2];
  const float* etab = (const float*)d_in[3];

  char* ws = (char*)d_ws;
  size_t off = 0;
  auto alloc = [&](size_t bytes) -> char* {
    char* p = ws + off;
    off += (bytes + 255) & ~(size_t)255;
    return p;
  };
  // small, permanent
  unsigned short* wih_c0 = (unsigned short*)alloc((size_t)2048 * 128 * 2);
  unsigned short* wih_c1 = (unsigned short*)alloc((size_t)2048 * 512 * 2);
  unsigned short* wih_w0 = (unsigned short*)alloc((size_t)2048 * 768 * 2);
  unsigned short* wih_w1 = (unsigned short*)alloc((size_t)2048 * 512 * 2);
  unsigned short* cls1b  = (unsigned short*)alloc((size_t)512 * 1024 * 2);
  unsigned short* cls2b  = (unsigned short*)alloc((size_t)15 * 512 * 2);
  uint2* whh_c0 = (uint2*)alloc((size_t)65536 * 8);
  uint2* whh_c1 = (uint2*)alloc((size_t)65536 * 8);
  uint2* whh_w0 = (uint2*)alloc((size_t)65536 * 8);
  uint2* whh_w1 = (uint2*)alloc((size_t)65536 * 8);
  float* bs_c0 = (float*)alloc(2048 * 4);
  float* bs_c1 = (float*)alloc(2048 * 4);
  float* bs_w0 = (float*)alloc(2048 * 4);
  float* bs_w1 = (float*)alloc(2048 * 4);
  float* numb = (float*)alloc(64 * 4);
  float* denb = (float*)alloc(64 * 4);
  // big
  unsigned short* comb = (unsigned short*)alloc((size_t)M * 1024 * 2);   // 64 MB
  unsigned short* xg_c = (unsigned short*)alloc((size_t)M * 2048 * 2);   // 128 MB
  const size_t xgw_bytes = (size_t)M * 2048 * 2;
  const bool fused = (off + xgw_bytes) <= ws_size;
  unsigned short* xg_w;
  unsigned short* ce_b;
  if (fused) {
    xg_w = (unsigned short*)alloc(xgw_bytes);
    ce_b = xg_w;                                   // gemm c0 consumes before gemm w0 writes
  } else {
    xg_w = xg_c;
    ce_b = (unsigned short*)alloc((size_t)M * 128 * 2);
  }
  unsigned short* h1 = xg_c;                        // free after level-1 lstm
  float* logits = (float*)(xg_c + (size_t)24 * 1024 * 1024);   // +48MB into xg_c

  // ---- prep ----
  cvt_bf16<<<1024, 256, 0, stream>>>((const float*)d_in[4],  wih_c0, 2048 * 128);
  cvt_bf16<<<1024, 256, 0, stream>>>((const float*)d_in[8],  wih_c1, 2048 * 512);
  cvt_bf16<<<1024, 256, 0, stream>>>((const float*)d_in[12], wih_w0, 2048 * 768);
  cvt_bf16<<<1024, 256, 0, stream>>>((const float*)d_in[16], wih_w1, 2048 * 512);
  cvt_bf16<<<1024, 256, 0, stream>>>((const float*)d_in[20], cls1b, 512 * 1024);
  cvt_bf16<<<64, 256, 0, stream>>>((const float*)d_in[22], cls2b, 15 * 512);
  whh_pack<<<256, 256, 0, stream>>>((const float*)d_in[5],  whh_c0);
  whh_pack<<<256, 256, 0, stream>>>((const float*)d_in[9],  whh_c1);
  whh_pack<<<256, 256, 0, stream>>>((const float*)d_in[13], whh_w0);
  whh_pack<<<256, 256, 0, stream>>>((const float*)d_in[17], whh_w1);
  bias_sum<<<8, 256, 0, stream>>>((const float*)d_in[6],  (const float*)d_in[7],  bs_c0, 2048);
  bias_sum<<<8, 256, 0, stream>>>((const float*)d_in[10], (const float*)d_in[11], bs_c1, 2048);
  bias_sum<<<8, 256, 0, stream>>>((const float*)d_in[14], (const float*)d_in[15], bs_w0, 2048);
  bias_sum<<<8, 256, 0, stream>>>((const float*)d_in[18], (const float*)d_in[19], bs_w1, 2048);
  embed_gather<<<8192, 256, 0, stream>>>(cid, etab, ce_b, M * 128);

  if (fused) {
    gemm_bt<0, 0, 1><<<512 * 8, 256, 0, stream>>>(ce_b, 128, wih_c0, bs_c0, xg_c, M, 2048, 128);
    gemm_bt<0, 1, 1><<<512 * 8, 256, 0, stream>>>(we, 768, wih_w0, bs_w0, xg_w, M, 2048, 768);
    lstm_mfma<<<16, 1024, 0, stream>>>(whh_c0, xg_c, comb, 0,
                                       whh_w0, xg_w, comb, 512, T);
    gemm_bt<0, 0, 1><<<512 * 8, 256, 0, stream>>>(comb, 1024, wih_c1, bs_c1, xg_c, M, 2048, 512);
    gemm_bt<0, 0, 1><<<512 * 8, 256, 0, stream>>>(comb + 512, 1024, wih_w1, bs_w1, xg_w, M, 2048, 512);
    lstm_mfma<<<16, 1024, 0, stream>>>(whh_c1, xg_c, comb, 0,
                                       whh_w1, xg_w, comb, 512, T);
  } else {
    gemm_bt<0, 0, 1><<<512 * 8, 256, 0, stream>>>(ce_b, 128, wih_c0, bs_c0, xg_c, M, 2048, 128);
    lstm_mfma<<<8, 1024, 0, stream>>>(whh_c0, xg_c, comb, 0, whh_c0, xg_c, comb, 0, T);
    gemm_bt<0, 0, 1><<<512 * 8, 256, 0, stream>>>(comb, 1024, wih_c1, bs_c1, xg_c, M, 2048, 512);
    lstm_mfma<<<8, 1024, 0, stream>>>(whh_c1, xg_c, comb, 0, whh_c1, xg_c, comb, 0, T);
    gemm_bt<0, 1, 1><<<512 * 8, 256, 0, stream>>>(we, 768, wih_w0, bs_w0, xg_c, M, 2048, 768);
    lstm_mfma<<<8, 1024, 0, stream>>>(whh_w0, xg_c, comb, 512, whh_w0, xg_c, comb, 512, T);
    gemm_bt<0, 0, 1><<<512 * 8, 256, 0, stream>>>(comb + 512, 1024, wih_w1, bs_w1, xg_c, M, 2048, 512);
    lstm_mfma<<<8, 1024, 0, stream>>>(whh_w1, xg_c, comb, 512, whh_w1, xg_c, comb, 512, T);
  }
  // ---- classifier ----
  gemm_bt<1, 0, 0><<<512 * 2, 256, 0, stream>>>(comb, 1024, cls1b, (const float*)d_in[21], h1, M, 512, 1024);
  cls2_kernel<<<2048, 256, 0, stream>>>(h1, cls2b, (const float*)d_in[23], logits, M);
  // ---- CRF ----
  crf_num<<<64, 256, 0, stream>>>(logits, tags, (const float*)d_in[24], (const float*)d_in[25],
                                  (const float*)d_in[26], numb, T);
  crf_denom<<<64, 64, 0, stream>>>(logits, (const float*)d_in[24], (const float*)d_in[25],
                                   (const float*)d_in[26], denb, T);
  crf_final<<<1, 64, 0, stream>>>(numb, denb, (float*)d_out);
}